// Round 8
// baseline (397.616 us; speedup 1.0000x reference)
//
#include <hip/hip_runtime.h>
#include <hip/hip_bf16.h>
#include <cstdint>
#include <cstddef>

// Problem constants: M=2048, D=1024, I=2048, E=8, TOPK=2
#define DDIM  1024
#define IDIM  2048
#define NEXP  8
#define NPAIR 4096
#define MAXTILE 40   // m-tiles (stride 128): 32 + 8 rounding

typedef __attribute__((ext_vector_type(8))) short short8;
typedef __attribute__((ext_vector_type(4))) float floatx4;
typedef __attribute__((ext_vector_type(4))) float fvec4;

__device__ inline short8 pack8v(fvec4 a, fvec4 b) {
    union { short8 s8; __hip_bfloat162 h[4]; } u;
    u.h[0] = __float22bfloat162_rn(float2{a.x, a.y});
    u.h[1] = __float22bfloat162_rn(float2{a.z, a.w});
    u.h[2] = __float22bfloat162_rn(float2{b.x, b.y});
    u.h[3] = __float22bfloat162_rn(float2{b.z, b.w});
    return u.s8;
}

__device__ inline void gload_lds16(const unsigned short* g, unsigned short* l) {
    __builtin_amdgcn_global_load_lds((const __attribute__((address_space(1))) void*)g,
                                     (__attribute__((address_space(3))) void*)l, 16, 0, 0);
}

// ============================================================================
// fp32 -> bf16 convert of x,w13,w2. Job = 1024 chunks; 8 independent 16B nt
// loads in flight per thread (sched_barrier pinned). R5 version (best).
// jobs: w13 [0,4096), w2 [4096,6144), x [6144,6400)
// ============================================================================
__launch_bounds__(256)
__global__ void cvt_all(const fvec4* __restrict__ x, const fvec4* __restrict__ w13,
                        const fvec4* __restrict__ w2,
                        uint4* __restrict__ xb, uint4* __restrict__ w13b,
                        uint4* __restrict__ w2b) {
    const int t = threadIdx.x;
    for (int job = blockIdx.x; job < 6400; job += gridDim.x) {
        const fvec4* src; uint4* dst; int cbase;
        if (job < 4096)      { src = w13; dst = w13b; cbase = job << 10; }
        else if (job < 6144) { src = w2;  dst = w2b;  cbase = (job - 4096) << 10; }
        else                 { src = x;   dst = xb;   cbase = (job - 6144) << 10; }
        const int c0 = cbase + t;
        fvec4 a0 = __builtin_nontemporal_load(src + 2 * (c0 + 0));
        fvec4 b0 = __builtin_nontemporal_load(src + 2 * (c0 + 0) + 1);
        fvec4 a1 = __builtin_nontemporal_load(src + 2 * (c0 + 256));
        fvec4 b1 = __builtin_nontemporal_load(src + 2 * (c0 + 256) + 1);
        fvec4 a2 = __builtin_nontemporal_load(src + 2 * (c0 + 512));
        fvec4 b2 = __builtin_nontemporal_load(src + 2 * (c0 + 512) + 1);
        fvec4 a3 = __builtin_nontemporal_load(src + 2 * (c0 + 768));
        fvec4 b3 = __builtin_nontemporal_load(src + 2 * (c0 + 768) + 1);
        __builtin_amdgcn_sched_barrier(0);
        short8 p0 = pack8v(a0, b0);
        short8 p1 = pack8v(a1, b1);
        short8 p2 = pack8v(a2, b2);
        short8 p3 = pack8v(a3, b3);
        dst[c0 + 0]   = *(uint4*)&p0;
        dst[c0 + 256] = *(uint4*)&p1;
        dst[c0 + 512] = *(uint4*)&p2;
        dst[c0 + 768] = *(uint4*)&p3;
    }
}

// ============================================================================
// Routing + dense tile table (stride 128). tbl[i] = {e, mbase, off0, ne}.
// ============================================================================
__global__ void route_kernel(const int* __restrict__ eidx,
                             int4* __restrict__ tbl,
                             int* __restrict__ slot_q) {
    __shared__ int cnt[NEXP];
    __shared__ int cur[NEXP];
    const int t = threadIdx.x;
    if (t < NEXP) cnt[t] = 0;
    __syncthreads();
    for (int q = t; q < NPAIR; q += 1024) atomicAdd(&cnt[eidx[q]], 1);
    __syncthreads();
    if (t == 0) {
        int s = 0, nt = 0;
        for (int e = 0; e < NEXP; e++) {
            cur[e] = s;
            for (int mb = 0; mb < cnt[e]; mb += 128)
                tbl[nt++] = int4{e, mb, s, cnt[e]};
            s += cnt[e];
        }
        for (; nt < MAXTILE; nt++) tbl[nt] = int4{0, 0, 0, 0};
    }
    __syncthreads();
    for (int q = t; q < NPAIR; q += 1024) {
        int e = eidx[q];
        int pos = atomicAdd(&cur[e], 1);
        slot_q[pos] = q;
    }
}

// ============================================================================
// GEMM1 + SwiGLU: 128(M) x 64(N out), BK=64. A: gload_lds depth-2 (LDS only
// 2x16KB). B: global->REGISTER double-buffer (named sets bA/bB, loop
// unrolled x2 for static indexing) — B loads issued one K-step ahead, fenced
// only by counted vmcnt(12) = 4(A)+8(B) newer; they fly across barriers and
// compute, never waiting at B1. Fragment addr from global: row*DDIM + ko +
// (h*4+quad)*8 (the LDS XOR path un-swizzled; identical MFMA operand bytes).
// ============================================================================
__launch_bounds__(256)
__global__ void gemm1_swiglu(const unsigned short* __restrict__ xb,
                             const unsigned short* __restrict__ w13b,
                             const int4* __restrict__ tbl,
                             const int* __restrict__ slot_q,
                             unsigned short* __restrict__ pbuf) {
    const int4 tt = tbl[blockIdx.y];
    const int e = tt.x, mbase = tt.y, off0 = tt.z, ne = tt.w;
    if (mbase >= ne) return;
    const int n0 = blockIdx.x * 64;

    __shared__ __align__(16) unsigned short As[2][128 * 64];   // 32KB total

    const int t    = threadIdx.x;
    const int lane = t & 63;
    const int wid  = t >> 6;

    // A staging (XOR-8 swizzle, unchanged)
    const int rr = t >> 3;
    const int g  = (t & 7) ^ (rr & 7);
    const unsigned short* pA[4];
    #pragma unroll
    for (int c = 0; c < 4; c++) {
        int row = c * 32 + rr;                      // 0..127
        int sl = mbase + row; if (sl > ne - 1) sl = ne - 1;
        pA[c] = xb + (size_t)(slot_q[off0 + sl] >> 1) * DDIM + g * 8;
    }
    const int lo = wid * 512;

    const int wm = wid >> 1, wn = wid & 1;
    const int quad = lane >> 4, l16 = lane & 15;
    const int rsw = l16 & 7;
    const int co0 = (quad ^ rsw) * 8;
    const int co1 = ((quad + 4) ^ rsw) * 8;

    // B bases: per-lane row pointers + quad k-chunk (shorts)
    const unsigned short* wb1 = w13b + (size_t)e * (2 * IDIM) * DDIM;
    const int r0 = n0 + wn * 32 + l16;
    const unsigned short* b1n0 = wb1 + (size_t)(r0)            * DDIM + quad * 8;
    const unsigned short* b1n1 = wb1 + (size_t)(r0 + 16)       * DDIM + quad * 8;
    const unsigned short* b3n0 = wb1 + (size_t)(IDIM + r0)     * DDIM + quad * 8;
    const unsigned short* b3n1 = wb1 + (size_t)(IDIM + r0 + 16)* DDIM + quad * 8;

    short8 bA[2][2][2], bB[2][2][2];   // [mat][h][ni], two named sets

#define LOADB1(dst, ko) {                                        \
    dst[0][0][0] = *(const short8*)(b1n0 + (ko));                \
    dst[0][0][1] = *(const short8*)(b1n1 + (ko));                \
    dst[0][1][0] = *(const short8*)(b1n0 + (ko) + 32);           \
    dst[0][1][1] = *(const short8*)(b1n1 + (ko) + 32);           \
    dst[1][0][0] = *(const short8*)(b3n0 + (ko));                \
    dst[1][0][1] = *(const short8*)(b3n1 + (ko));                \
    dst[1][1][0] = *(const short8*)(b3n0 + (ko) + 32);           \
    dst[1][1][1] = *(const short8*)(b3n1 + (ko) + 32);           \
}

    floatx4 acc1[4][2], acc3[4][2];
    #pragma unroll
    for (int i = 0; i < 4; i++)
        #pragma unroll
        for (int j = 0; j < 2; j++) {
            acc1[i][j] = floatx4{0.f, 0.f, 0.f, 0.f};
            acc3[i][j] = floatx4{0.f, 0.f, 0.f, 0.f};
        }

#define COMPUTE1(bufi, breg) {                                                     \
    __builtin_amdgcn_s_setprio(1);                                                 \
    _Pragma("unroll")                                                              \
    for (int h = 0; h < 2; ++h) {                                                  \
        const int co = h ? co1 : co0;                                              \
        short8 af[4];                                                              \
        _Pragma("unroll")                                                          \
        for (int mi = 0; mi < 4; mi++)                                             \
            af[mi] = *(short8*)&As[bufi][(wm * 64 + mi * 16 + l16) * 64 + co];     \
        _Pragma("unroll")                                                          \
        for (int mi = 0; mi < 4; mi++)                                             \
            _Pragma("unroll")                                                      \
            for (int ni = 0; ni < 2; ni++) {                                       \
                acc1[mi][ni] = __builtin_amdgcn_mfma_f32_16x16x32_bf16(af[mi], breg[0][h][ni], acc1[mi][ni], 0, 0, 0); \
                acc3[mi][ni] = __builtin_amdgcn_mfma_f32_16x16x32_bf16(af[mi], breg[1][h][ni], acc3[mi][ni], 0, 0, 0); \
            }                                                                      \
    }                                                                              \
    __builtin_amdgcn_s_setprio(0);                                                 \
}

    // prologue: A0 -> buf0, B0 -> bA
    #pragma unroll
    for (int c = 0; c < 4; c++) gload_lds16(pA[c], &As[0][lo + c * 2048]);
    LOADB1(bA, 0);
    __builtin_amdgcn_sched_barrier(0);

    for (int j = 0; j < 8; ++j) {                   // 16 K-steps, 2 per iter
        // ---- body A: compute step 2j (buf0, bA); prefetch 2j+1 ----
        {
            const int ko = (2 * j + 1) * 64;
            #pragma unroll
            for (int c = 0; c < 4; c++) gload_lds16(pA[c] + ko, &As[1][lo + c * 2048]);
            LOADB1(bB, ko);
            __builtin_amdgcn_sched_barrier(0);
            asm volatile("s_waitcnt vmcnt(12)" ::: "memory");  // step-2j batch landed
            __builtin_amdgcn_s_barrier();                      // B1
            __builtin_amdgcn_sched_barrier(0);
            COMPUTE1(0, bA);
            __builtin_amdgcn_s_barrier();                      // B2
            __builtin_amdgcn_sched_barrier(0);
        }
        // ---- body B: compute step 2j+1 (buf1, bB); prefetch 2j+2 ----
        {
            if (2 * j + 2 < 16) {
                const int ko = (2 * j + 2) * 64;
                #pragma unroll
                for (int c = 0; c < 4; c++) gload_lds16(pA[c] + ko, &As[0][lo + c * 2048]);
                LOADB1(bA, ko);
                __builtin_amdgcn_sched_barrier(0);
                asm volatile("s_waitcnt vmcnt(12)" ::: "memory");
            } else {
                asm volatile("s_waitcnt vmcnt(0)" ::: "memory");
            }
            __builtin_amdgcn_s_barrier();                      // B1
            __builtin_amdgcn_sched_barrier(0);
            COMPUTE1(1, bB);
            __builtin_amdgcn_s_barrier();                      // B2
            __builtin_amdgcn_sched_barrier(0);
        }
    }

    #pragma unroll
    for (int mi = 0; mi < 4; mi++) {
        #pragma unroll
        for (int ni = 0; ni < 2; ni++) {
            const int col = n0 + wn * 32 + ni * 16 + l16;
            #pragma unroll
            for (int rw = 0; rw < 4; rw++) {
                const int s2 = mbase + wm * 64 + mi * 16 + quad * 4 + rw;
                if (s2 < ne) {
                    float v1 = acc1[mi][ni][rw];
                    float v3 = acc3[mi][ni][rw];
                    float pv = v1 / (1.f + __expf(-v1)) * v3;
                    __hip_bfloat16 pb = __float2bfloat16(pv);
                    pbuf[(size_t)(off0 + s2) * IDIM + col] = *(unsigned short*)&pb;
                }
            }
        }
    }
#undef LOADB1
#undef COMPUTE1
}

// ============================================================================
// GEMM2: 128(M) x 64(N), full K=2048, direct fp32 store to out. Same
// transform: A via gload_lds depth-2 (32KB LDS), B (w2) global->reg
// double-buffer, counted vmcnt(8) = 4(A)+4(B). grid (16, MAXTILE).
// ============================================================================
__launch_bounds__(256)
__global__ void gemm2_out(const unsigned short* __restrict__ pbuf,
                          const unsigned short* __restrict__ w2b,
                          const int4* __restrict__ tbl,
                          const int* __restrict__ slot_q,
                          float* __restrict__ out) {
    const int4 tt = tbl[blockIdx.y];
    const int e = tt.x, mbase = tt.y, off0 = tt.z, ne = tt.w;
    if (mbase >= ne) return;
    const int n0 = blockIdx.x * 64;

    __shared__ __align__(16) unsigned short As[2][128 * 64];   // 32KB

    const int t    = threadIdx.x;
    const int lane = t & 63;
    const int wid  = t >> 6;

    const int rr = t >> 3;
    const int g  = (t & 7) ^ (rr & 7);
    const unsigned short* pA[4];
    #pragma unroll
    for (int c = 0; c < 4; c++) {
        int row = c * 32 + rr;                      // 0..127
        int sl = mbase + row; if (sl > ne - 1) sl = ne - 1;
        pA[c] = pbuf + (size_t)(off0 + sl) * IDIM + g * 8;
    }
    const int lo = wid * 512;

    const int wm = wid >> 1, wn = wid & 1;
    const int quad = lane >> 4, l16 = lane & 15;
    const int rsw = l16 & 7;
    const int co0 = (quad ^ rsw) * 8;
    const int co1 = ((quad + 4) ^ rsw) * 8;

    const unsigned short* wb = w2b + (size_t)e * DDIM * IDIM;
    const int r0 = n0 + wn * 32 + l16;
    const unsigned short* bn0 = wb + (size_t)(r0)      * IDIM + quad * 8;
    const unsigned short* bn1 = wb + (size_t)(r0 + 16) * IDIM + quad * 8;

    short8 bA[2][2], bB[2][2];   // [h][ni]

#define LOADB2(dst, ko) {                              \
    dst[0][0] = *(const short8*)(bn0 + (ko));          \
    dst[0][1] = *(const short8*)(bn1 + (ko));          \
    dst[1][0] = *(const short8*)(bn0 + (ko) + 32);     \
    dst[1][1] = *(const short8*)(bn1 + (ko) + 32);     \
}

    floatx4 acc[4][2];
    #pragma unroll
    for (int i = 0; i < 4; i++)
        #pragma unroll
        for (int j = 0; j < 2; j++) acc[i][j] = floatx4{0.f, 0.f, 0.f, 0.f};

#define COMPUTE2(bufi, breg) {                                                     \
    __builtin_amdgcn_s_setprio(1);                                                 \
    _Pragma("unroll")                                                              \
    for (int h = 0; h < 2; ++h) {                                                  \
        const int co = h ? co1 : co0;                                              \
        short8 af[4];                                                              \
        _Pragma("unroll")                                                          \
        for (int mi = 0; mi < 4; mi++)                                             \
            af[mi] = *(short8*)&As[bufi][(wm * 64 + mi * 16 + l16) * 64 + co];     \
        _Pragma("unroll")                                                          \
        for (int mi = 0; mi < 4; mi++)                                             \
            _Pragma("unroll")                                                      \
            for (int ni = 0; ni < 2; ni++)                                         \
                acc[mi][ni] = __builtin_amdgcn_mfma_f32_16x16x32_bf16(af[mi], breg[h][ni], acc[mi][ni], 0, 0, 0); \
    }                                                                              \
    __builtin_amdgcn_s_setprio(0);                                                 \
}

    // prologue
    #pragma unroll
    for (int c = 0; c < 4; c++) gload_lds16(pA[c], &As[0][lo + c * 2048]);
    LOADB2(bA, 0);
    __builtin_amdgcn_sched_barrier(0);

    for (int j = 0; j < 16; ++j) {                  // 32 K-steps, 2 per iter
        {   // body A: step 2j
            const int ko = (2 * j + 1) * 64;
            #pragma unroll
            for (int c = 0; c < 4; c++) gload_lds16(pA[c] + ko, &As[1][lo + c * 2048]);
            LOADB2(bB, ko);
            __builtin_amdgcn_sched_barrier(0);
            asm volatile("s_waitcnt vmcnt(8)" ::: "memory");
            __builtin_amdgcn_s_barrier();
            __builtin_amdgcn_sched_barrier(0);
            COMPUTE2(0, bA);
            __builtin_amdgcn_s_barrier();
            __builtin_amdgcn_sched_barrier(0);
        }
        {   // body B: step 2j+1
            if (2 * j + 2 < 32) {
                const int ko = (2 * j + 2) * 64;
                #pragma unroll
                for (int c = 0; c < 4; c++) gload_lds16(pA[c] + ko, &As[0][lo + c * 2048]);
                LOADB2(bA, ko);
                __builtin_amdgcn_sched_barrier(0);
                asm volatile("s_waitcnt vmcnt(8)" ::: "memory");
            } else {
                asm volatile("s_waitcnt vmcnt(0)" ::: "memory");
            }
            __builtin_amdgcn_s_barrier();
            __builtin_amdgcn_sched_barrier(0);
            COMPUTE2(1, bB);
            __builtin_amdgcn_s_barrier();
            __builtin_amdgcn_sched_barrier(0);
        }
    }

    #pragma unroll
    for (int mi = 0; mi < 4; mi++) {
        #pragma unroll
        for (int rw = 0; rw < 4; rw++) {
            const int s2 = mbase + wm * 64 + mi * 16 + quad * 4 + rw;
            if (s2 < ne) {
                const int qq = slot_q[off0 + s2];
                float* orow = out + (size_t)qq * DDIM;
                #pragma unroll
                for (int ni = 0; ni < 2; ni++)
                    orow[n0 + wn * 32 + ni * 16 + l16] = acc[mi][ni][rw];
            }
        }
    }
#undef LOADB2
#undef COMPUTE2
}

// ============================================================================
extern "C" void kernel_launch(void* const* d_in, const int* in_sizes, int n_in,
                              void* d_out, int out_size, void* d_ws, size_t ws_size,
                              hipStream_t stream) {
    const float* x    = (const float*)d_in[0];
    const float* w13  = (const float*)d_in[1];
    const float* w2   = (const float*)d_in[2];
    const int*   eidx = (const int*)d_in[3];
    float* out = (float*)d_out;

    // ws layout:
    //   [128,768) tile tbl; [1024,17408) slot_q; [OFF_XB,+4MB) xb;
    //   [OFF_W13B,+64MB) w13b; [OFF_W2B,+32MB) w2b; [OFF_PBUF,+16MB) pbuf
    const size_t OFF_XB   = 65536;
    const size_t OFF_W13B = OFF_XB + (size_t)4 * 1024 * 1024;
    const size_t OFF_W2B  = OFF_W13B + (size_t)64 * 1024 * 1024;
    const size_t OFF_PBUF = OFF_W2B + (size_t)32 * 1024 * 1024;

    int4* tbl   = (int4*)((char*)d_ws + 128);
    int* slot_q = (int*)((char*)d_ws + 1024);
    unsigned short* xb   = (unsigned short*)((char*)d_ws + OFF_XB);
    unsigned short* w13b = (unsigned short*)((char*)d_ws + OFF_W13B);
    unsigned short* w2b  = (unsigned short*)((char*)d_ws + OFF_W2B);
    unsigned short* pbuf = (unsigned short*)((char*)d_ws + OFF_PBUF);

    hipLaunchKernelGGL(route_kernel, dim3(1), dim3(1024), 0, stream, eidx, tbl, slot_q);
    hipLaunchKernelGGL(cvt_all, dim3(6400), dim3(256), 0, stream,
                       (const fvec4*)x, (const fvec4*)w13, (const fvec4*)w2,
                       (uint4*)xb, (uint4*)w13b, (uint4*)w2b);
    hipLaunchKernelGGL(gemm1_swiglu, dim3(IDIM / 64, MAXTILE), dim3(256), 0, stream,
                       xb, w13b, tbl, slot_q, pbuf);
    hipLaunchKernelGGL(gemm2_out, dim3(DDIM / 64, MAXTILE), dim3(256), 0, stream,
                       pbuf, w2b, tbl, slot_q, out);
}

// Round 9
// 335.654 us; speedup vs baseline: 1.1846x; 1.1846x over previous
//
#include <hip/hip_runtime.h>
#include <hip/hip_bf16.h>
#include <cstdint>
#include <cstddef>

// Problem constants: M=2048, D=1024, I=2048, E=8, TOPK=2
#define DDIM  1024
#define IDIM  2048
#define NEXP  8
#define NPAIR 4096
#define MAXTILE 40   // m-tiles (stride 128): 32 + 8 rounding

typedef __attribute__((ext_vector_type(8))) short short8;
typedef __attribute__((ext_vector_type(4))) float floatx4;
typedef __attribute__((ext_vector_type(4))) float fvec4;

__device__ inline short8 pack8v(fvec4 a, fvec4 b) {
    union { short8 s8; __hip_bfloat162 h[4]; } u;
    u.h[0] = __float22bfloat162_rn(float2{a.x, a.y});
    u.h[1] = __float22bfloat162_rn(float2{a.z, a.w});
    u.h[2] = __float22bfloat162_rn(float2{b.x, b.y});
    u.h[3] = __float22bfloat162_rn(float2{b.z, b.w});
    return u.s8;
}

__device__ inline void gload_lds16(const unsigned short* g, unsigned short* l) {
    __builtin_amdgcn_global_load_lds((const __attribute__((address_space(1))) void*)g,
                                     (__attribute__((address_space(3))) void*)l, 16, 0, 0);
}

// ============================================================================
// fp32 -> bf16 convert of x,w13,w2. Job = 1024 chunks; 8 independent 16B nt
// loads in flight per thread (sched_barrier pinned). R5 version (best).
// jobs: w13 [0,4096), w2 [4096,6144), x [6144,6400)
// ============================================================================
__launch_bounds__(256)
__global__ void cvt_all(const fvec4* __restrict__ x, const fvec4* __restrict__ w13,
                        const fvec4* __restrict__ w2,
                        uint4* __restrict__ xb, uint4* __restrict__ w13b,
                        uint4* __restrict__ w2b) {
    const int t = threadIdx.x;
    for (int job = blockIdx.x; job < 6400; job += gridDim.x) {
        const fvec4* src; uint4* dst; int cbase;
        if (job < 4096)      { src = w13; dst = w13b; cbase = job << 10; }
        else if (job < 6144) { src = w2;  dst = w2b;  cbase = (job - 4096) << 10; }
        else                 { src = x;   dst = xb;   cbase = (job - 6144) << 10; }
        const int c0 = cbase + t;
        fvec4 a0 = __builtin_nontemporal_load(src + 2 * (c0 + 0));
        fvec4 b0 = __builtin_nontemporal_load(src + 2 * (c0 + 0) + 1);
        fvec4 a1 = __builtin_nontemporal_load(src + 2 * (c0 + 256));
        fvec4 b1 = __builtin_nontemporal_load(src + 2 * (c0 + 256) + 1);
        fvec4 a2 = __builtin_nontemporal_load(src + 2 * (c0 + 512));
        fvec4 b2 = __builtin_nontemporal_load(src + 2 * (c0 + 512) + 1);
        fvec4 a3 = __builtin_nontemporal_load(src + 2 * (c0 + 768));
        fvec4 b3 = __builtin_nontemporal_load(src + 2 * (c0 + 768) + 1);
        __builtin_amdgcn_sched_barrier(0);
        short8 p0 = pack8v(a0, b0);
        short8 p1 = pack8v(a1, b1);
        short8 p2 = pack8v(a2, b2);
        short8 p3 = pack8v(a3, b3);
        dst[c0 + 0]   = *(uint4*)&p0;
        dst[c0 + 256] = *(uint4*)&p1;
        dst[c0 + 512] = *(uint4*)&p2;
        dst[c0 + 768] = *(uint4*)&p3;
    }
}

// ============================================================================
// Routing + dense tile table (stride 128). tbl[i] = {e, mbase, off0, ne}.
// ============================================================================
__global__ void route_kernel(const int* __restrict__ eidx,
                             int4* __restrict__ tbl,
                             int* __restrict__ slot_q) {
    __shared__ int cnt[NEXP];
    __shared__ int cur[NEXP];
    const int t = threadIdx.x;
    if (t < NEXP) cnt[t] = 0;
    __syncthreads();
    for (int q = t; q < NPAIR; q += 1024) atomicAdd(&cnt[eidx[q]], 1);
    __syncthreads();
    if (t == 0) {
        int s = 0, nt = 0;
        for (int e = 0; e < NEXP; e++) {
            cur[e] = s;
            for (int mb = 0; mb < cnt[e]; mb += 128)
                tbl[nt++] = int4{e, mb, s, cnt[e]};
            s += cnt[e];
        }
        for (; nt < MAXTILE; nt++) tbl[nt] = int4{0, 0, 0, 0};
    }
    __syncthreads();
    for (int q = t; q < NPAIR; q += 1024) {
        int e = eidx[q];
        int pos = atomicAdd(&cur[e], 1);
        slot_q[pos] = q;
    }
}

// ============================================================================
// GEMM1 + SwiGLU: 128(M) x 128(N out) tile (Bs = 256 rows: 128 w1 + 128 w3),
// BK=64, *** 512 threads = 8 waves (2M x 4N) ***. Per-wave geometry is
// identical to the proven R2 kernel (64M x 32N-out, acc[4][2] x2). Rationale:
// staged bytes drop 22% vs 128x64 (A-pass halves: 435 vs 557 MB total) while
// waves/CU stays at 17 (2.1 blocks/CU x 8 waves) -- R7's version lost because
// its 4-wave blocks halved resident waves; this keeps them.
// LDS 48KB (As 16K + Bs 32K) -> 3 blocks/CU possible, grid-capped at 2.1.
// Single-buffered, 2-syncthreads structure (R2's proven form).
// grid: (IDIM/128=16, MAXTILE).
// ============================================================================
__launch_bounds__(512)
__global__ void gemm1_swiglu(const unsigned short* __restrict__ xb,
                             const unsigned short* __restrict__ w13b,
                             const int4* __restrict__ tbl,
                             const int* __restrict__ slot_q,
                             unsigned short* __restrict__ pbuf) {
    const int4 tt = tbl[blockIdx.y];
    const int e = tt.x, mbase = tt.y, off0 = tt.z, ne = tt.w;
    if (mbase >= ne) return;
    const int n0 = blockIdx.x * 128;

    __shared__ __align__(16) unsigned short As[128 * 64];   // 16KB
    __shared__ __align__(16) unsigned short Bs[256 * 64];   // 32KB

    const int t    = threadIdx.x;
    const int lane = t & 63;
    const int wid  = t >> 6;              // 0..7

    // staging: 512 thr x 16B = 64 rows per issue. rr = t>>3 in 0..63,
    // dest chunk p = t&7, source chunk g = p ^ (row&7) = p ^ (rr&7)
    // (row = c*64 + rr, c*64 multiple of 8 -> row&7 == rr&7).
    const int rr = t >> 3;
    const int g  = (t & 7) ^ (rr & 7);
    const unsigned short* pA[2];
    const unsigned short* pB[4];
    const unsigned short* wb1 = w13b + (size_t)e * (2 * IDIM) * DDIM;
    #pragma unroll
    for (int c = 0; c < 2; c++) {
        int row = c * 64 + rr;                      // 0..127
        int sl = mbase + row; if (sl > ne - 1) sl = ne - 1;
        pA[c] = xb + (size_t)(slot_q[off0 + sl] >> 1) * DDIM + g * 8;
    }
    #pragma unroll
    for (int c = 0; c < 4; c++) {
        int row = c * 64 + rr;                      // 0..255
        int wrow = (row < 128) ? (n0 + row) : (IDIM + n0 + (row - 128)); // w1|w3
        pB[c] = wb1 + (size_t)wrow * DDIM + g * 8;
    }
    unsigned short* lA = As + wid * 512;   // + c*4096 (issue = 64 rows = 4096 shorts)
    unsigned short* lB = Bs + wid * 512;

    const int wm = wid >> 2, wn = wid & 3;          // 2M x 4N
    const int quad = lane >> 4, l16 = lane & 15;
    const int rsw = l16 & 7;
    const int co0 = (quad ^ rsw) * 8;         // k-half 0 chunk offset (shorts)
    const int co1 = ((quad + 4) ^ rsw) * 8;   // k-half 1

    floatx4 acc1[4][2], acc3[4][2];
    #pragma unroll
    for (int i = 0; i < 4; i++)
        #pragma unroll
        for (int j = 0; j < 2; j++) {
            acc1[i][j] = floatx4{0.f, 0.f, 0.f, 0.f};
            acc3[i][j] = floatx4{0.f, 0.f, 0.f, 0.f};
        }

    for (int it = 0; it < DDIM / 64; ++it) {        // 16 K-steps
        const int ko = it * 64;
        __syncthreads();
        #pragma unroll
        for (int c = 0; c < 2; c++)
            gload_lds16(pA[c] + ko, lA + c * 4096);
        #pragma unroll
        for (int c = 0; c < 4; c++)
            gload_lds16(pB[c] + ko, lB + c * 4096);
        __syncthreads();

        #pragma unroll
        for (int h = 0; h < 2; ++h) {
            const int co = h ? co1 : co0;
            short8 af[4], b1f[2], b3f[2];
            #pragma unroll
            for (int mi = 0; mi < 4; mi++)
                af[mi] = *(short8*)&As[(wm * 64 + mi * 16 + l16) * 64 + co];
            #pragma unroll
            for (int ni = 0; ni < 2; ni++) {
                b1f[ni] = *(short8*)&Bs[(wn * 32 + ni * 16 + l16) * 64 + co];
                b3f[ni] = *(short8*)&Bs[(128 + wn * 32 + ni * 16 + l16) * 64 + co];
            }
            #pragma unroll
            for (int mi = 0; mi < 4; mi++)
                #pragma unroll
                for (int ni = 0; ni < 2; ni++) {
                    acc1[mi][ni] = __builtin_amdgcn_mfma_f32_16x16x32_bf16(af[mi], b1f[ni], acc1[mi][ni], 0, 0, 0);
                    acc3[mi][ni] = __builtin_amdgcn_mfma_f32_16x16x32_bf16(af[mi], b3f[ni], acc3[mi][ni], 0, 0, 0);
                }
        }
    }

    #pragma unroll
    for (int mi = 0; mi < 4; mi++) {
        #pragma unroll
        for (int ni = 0; ni < 2; ni++) {
            const int col = n0 + wn * 32 + ni * 16 + l16;
            #pragma unroll
            for (int rw = 0; rw < 4; rw++) {
                const int s2 = mbase + wm * 64 + mi * 16 + quad * 4 + rw;
                if (s2 < ne) {
                    float v1 = acc1[mi][ni][rw];
                    float v3 = acc3[mi][ni][rw];
                    float pv = v1 / (1.f + __expf(-v1)) * v3;
                    __hip_bfloat16 pb = __float2bfloat16(pv);
                    pbuf[(size_t)(off0 + s2) * IDIM + col] = *(unsigned short*)&pb;
                }
            }
        }
    }
}

// ============================================================================
// GEMM2: 128(M) x 64(N), full K=2048, direct fp32 store to out. R5 version
// verbatim (best measured): depth-2 counted-vmcnt pipeline (6 loads/batch ->
// vmcnt(6)). LDS 48KB -> 3 blocks/CU. grid (16, MAXTILE).
// ============================================================================
__launch_bounds__(256)
__global__ void gemm2_out(const unsigned short* __restrict__ pbuf,
                          const unsigned short* __restrict__ w2b,
                          const int4* __restrict__ tbl,
                          const int* __restrict__ slot_q,
                          float* __restrict__ out) {
    const int4 tt = tbl[blockIdx.y];
    const int e = tt.x, mbase = tt.y, off0 = tt.z, ne = tt.w;
    if (mbase >= ne) return;
    const int n0 = blockIdx.x * 64;

    __shared__ __align__(16) unsigned short As[2][128 * 64];
    __shared__ __align__(16) unsigned short Bs[2][64 * 64];

    const int t    = threadIdx.x;
    const int lane = t & 63;
    const int wid  = t >> 6;

    const int rr = t >> 3;
    const int g  = (t & 7) ^ (rr & 7);
    const unsigned short* pA[4];
    const unsigned short* pB[2];
    const unsigned short* wb = w2b + (size_t)e * DDIM * IDIM;
    #pragma unroll
    for (int c = 0; c < 4; c++) {
        int row = c * 32 + rr;                      // 0..127
        int sl = mbase + row; if (sl > ne - 1) sl = ne - 1;
        pA[c] = pbuf + (size_t)(off0 + sl) * IDIM + g * 8;
    }
    #pragma unroll
    for (int c = 0; c < 2; c++) {
        int row = c * 32 + rr;                      // 0..63
        pB[c] = wb + (size_t)(n0 + row) * IDIM + g * 8;
    }
    const int lo = wid * 512;

    const int wm = wid >> 1, wn = wid & 1;
    const int quad = lane >> 4, l16 = lane & 15;
    const int rsw = l16 & 7;
    const int co0 = (quad ^ rsw) * 8;
    const int co1 = ((quad + 4) ^ rsw) * 8;

    floatx4 acc[4][2];
    #pragma unroll
    for (int i = 0; i < 4; i++)
        #pragma unroll
        for (int j = 0; j < 2; j++) acc[i][j] = floatx4{0.f, 0.f, 0.f, 0.f};

    // prologue: stage tile 0 into buf 0
    #pragma unroll
    for (int c = 0; c < 4; c++)
        gload_lds16(pA[c], &As[0][lo + c * 2048]);
    #pragma unroll
    for (int c = 0; c < 2; c++)
        gload_lds16(pB[c], &Bs[0][lo + c * 2048]);
    __builtin_amdgcn_sched_barrier(0);

    int cur = 0;
    for (int it = 0; it < IDIM / 64; ++it) {        // 32 K-steps
        if (it + 1 < IDIM / 64) {
            const int ko = (it + 1) * 64;
            #pragma unroll
            for (int c = 0; c < 4; c++)
                gload_lds16(pA[c] + ko, &As[cur ^ 1][lo + c * 2048]);
            #pragma unroll
            for (int c = 0; c < 2; c++)
                gload_lds16(pB[c] + ko, &Bs[cur ^ 1][lo + c * 2048]);
            __builtin_amdgcn_sched_barrier(0);
            asm volatile("s_waitcnt vmcnt(6)" ::: "memory");   // batch t landed
        } else {
            asm volatile("s_waitcnt vmcnt(0)" ::: "memory");
        }
        __builtin_amdgcn_s_barrier();               // B1
        __builtin_amdgcn_sched_barrier(0);

        __builtin_amdgcn_s_setprio(1);
        #pragma unroll
        for (int h = 0; h < 2; ++h) {
            const int co = h ? co1 : co0;
            short8 af[4], bf[2];
            #pragma unroll
            for (int mi = 0; mi < 4; mi++)
                af[mi] = *(short8*)&As[cur][(wm * 64 + mi * 16 + l16) * 64 + co];
            #pragma unroll
            for (int ni = 0; ni < 2; ni++)
                bf[ni] = *(short8*)&Bs[cur][(wn * 32 + ni * 16 + l16) * 64 + co];
            #pragma unroll
            for (int mi = 0; mi < 4; mi++)
                #pragma unroll
                for (int ni = 0; ni < 2; ni++)
                    acc[mi][ni] = __builtin_amdgcn_mfma_f32_16x16x32_bf16(af[mi], bf[ni], acc[mi][ni], 0, 0, 0);
        }
        __builtin_amdgcn_s_setprio(0);
        __builtin_amdgcn_s_barrier();               // B2
        __builtin_amdgcn_sched_barrier(0);
        cur ^= 1;
    }

    #pragma unroll
    for (int mi = 0; mi < 4; mi++) {
        #pragma unroll
        for (int rw = 0; rw < 4; rw++) {
            const int s2 = mbase + wm * 64 + mi * 16 + quad * 4 + rw;
            if (s2 < ne) {
                const int qq = slot_q[off0 + s2];
                float* orow = out + (size_t)qq * DDIM;
                #pragma unroll
                for (int ni = 0; ni < 2; ni++)
                    orow[n0 + wn * 32 + ni * 16 + l16] = acc[mi][ni][rw];
            }
        }
    }
}

// ============================================================================
extern "C" void kernel_launch(void* const* d_in, const int* in_sizes, int n_in,
                              void* d_out, int out_size, void* d_ws, size_t ws_size,
                              hipStream_t stream) {
    const float* x    = (const float*)d_in[0];
    const float* w13  = (const float*)d_in[1];
    const float* w2   = (const float*)d_in[2];
    const int*   eidx = (const int*)d_in[3];
    float* out = (float*)d_out;

    // ws layout:
    //   [128,768) tile tbl; [1024,17408) slot_q; [OFF_XB,+4MB) xb;
    //   [OFF_W13B,+64MB) w13b; [OFF_W2B,+32MB) w2b; [OFF_PBUF,+16MB) pbuf
    const size_t OFF_XB   = 65536;
    const size_t OFF_W13B = OFF_XB + (size_t)4 * 1024 * 1024;
    const size_t OFF_W2B  = OFF_W13B + (size_t)64 * 1024 * 1024;
    const size_t OFF_PBUF = OFF_W2B + (size_t)32 * 1024 * 1024;

    int4* tbl   = (int4*)((char*)d_ws + 128);
    int* slot_q = (int*)((char*)d_ws + 1024);
    unsigned short* xb   = (unsigned short*)((char*)d_ws + OFF_XB);
    unsigned short* w13b = (unsigned short*)((char*)d_ws + OFF_W13B);
    unsigned short* w2b  = (unsigned short*)((char*)d_ws + OFF_W2B);
    unsigned short* pbuf = (unsigned short*)((char*)d_ws + OFF_PBUF);

    hipLaunchKernelGGL(route_kernel, dim3(1), dim3(1024), 0, stream, eidx, tbl, slot_q);
    hipLaunchKernelGGL(cvt_all, dim3(6400), dim3(256), 0, stream,
                       (const fvec4*)x, (const fvec4*)w13, (const fvec4*)w2,
                       (uint4*)xb, (uint4*)w13b, (uint4*)w2b);
    hipLaunchKernelGGL(gemm1_swiglu, dim3(IDIM / 128, MAXTILE), dim3(512), 0, stream,
                       xb, w13b, tbl, slot_q, pbuf);
    hipLaunchKernelGGL(gemm2_out, dim3(DDIM / 64, MAXTILE), dim3(256), 0, stream,
                       pbuf, w2b, tbl, slot_q, out);
}